// Round 13
// baseline (310.330 us; speedup 1.0000x reference)
//
#include <hip/hip_runtime.h>
#include <hip/hip_bf16.h>

constexpr int B_  = 8;
constexpr int N1_ = 8192;
constexpr int N2_ = 2048;
constexpr int K_  = 8;

typedef short bf16x8 __attribute__((ext_vector_type(8)));
typedef float f32x4  __attribute__((ext_vector_type(4)));
typedef float f32x2  __attribute__((ext_vector_type(2)));

__device__ __forceinline__ short f2b(float x) {
    __hip_bfloat16 h = __float2bfloat16(x);  // RNE
    return *reinterpret_cast<short*>(&h);
}

// float CAS: for non-negative floats ordering == uint-bit ordering; emits
// v_min_f32/v_max_f32 (2 instr) instead of cmp+2*cndmask.
#define CASF(a, b) { const float _lo = fminf(a, b); \
                     const float _hi = fmaxf(a, b); \
                     (a) = _lo; (b) = _hi; }

// ---------------------------------------------------------------------------
// MERGED prep+knn (r13 = r12 + packed-f32 distances): blocks 0..1023 = KNN
// v10; blocks 1024..3071 = feat2 f32->bf16; blocks 3072..3311 = weights.
// KNN v10: AoS broadcast loads (8 pts = 96B, 6 dwordx4, wave-uniform) +
// f32x2-packed distance math (v_pk_sub/mul/fma: 2 pts per instr). r12
// measured VALUBusy 77.6% (issue-bound) -> packed dist cuts ~15 issue
// slots/batch. Scan values contract-fast/packed (loose <=~3ulp); accept
// threshold *(1+2^-18) keeps the listed set a superset of the exact top-8
// (same proof as r4/r10/r12, all PASSED); recovery + overflow fallback
// replay contract(off) from the SAME AoS floats => final idx BIT-EXACT.
// ---------------------------------------------------------------------------
constexpr int LCAP = 76;   // data slots 0..75; rows 76,77 = trash (78 rows)

__global__ __launch_bounds__(256) void prep_knn(
    const float* __restrict__ xyz1, const float* __restrict__ xyz2,
    const float* __restrict__ feat2,
    const float* __restrict__ W0, const float* __restrict__ W1,
    const float* __restrict__ W2,
    int* __restrict__ idx, short* __restrict__ feat2b,
    short* __restrict__ W0T, short* __restrict__ W1T, short* __restrict__ W2T) {
    const int tid = threadIdx.x;

    if (blockIdx.x >= 1024) {
        int i = (blockIdx.x - 1024) * 256 + tid;
        if (i < 2048 * 256) {  // feat2 -> bf16, 4 elems/thread
            const float4 v = ((const float4*)feat2)[i];
            uint2 o;
            o.x = (unsigned short)f2b(v.x) | ((unsigned)(unsigned short)f2b(v.y) << 16);
            o.y = (unsigned short)f2b(v.z) | ((unsigned)(unsigned short)f2b(v.w) << 16);
            ((uint2*)feat2b)[i] = o;
            return;
        }
        i -= 2048 * 256;
        if (i < 128 * 160) {
            const int n = i / 160, k = i % 160;
            W0T[i] = (k < 131) ? f2b(W0[k * 128 + n]) : (short)0;
            return;
        }
        i -= 128 * 160;
        if (i < 128 * 128) {
            const int n = i >> 7, k = i & 127;
            W1T[i] = f2b(W1[k * 128 + n]);
            return;
        }
        i -= 128 * 128;
        const int n = i / 192, k = i % 192;
        W2T[i] = f2b(W2[k * 128 + n]);
        return;
    }

    // ===================== KNN v10 (blocks 0..1023) ========================
    __shared__ __align__(16) unsigned short sMem[78 * 256];  // 39936 B, [slot][tid]
    float* sD = (float*)sMem;             // [64][33] overlay after recovery
    int*   sI = (int*)sMem + 64 * 33;

    const int b = blockIdx.x & 7;        // batch
    const int t64 = blockIdx.x >> 3;     // 64-query tile
    const int lane = tid & 63;           // query within block
    const int s = tid >> 6;              // segment 0..3
    const int n = t64 * 64 + lane;

    const float* q = xyz1 + ((size_t)b * N1_ + n) * 3;
    const float qx = q[0], qy = q[1], qz = q[2];
    const float* P = xyz2 + ((size_t)b * N2_ + s * 512) * 3;  // AoS, 512 pts

    float bd[K_];
#pragma unroll
    for (int t = 0; t < K_; ++t) bd[t] = 3.0e38f;
    int cnt = 0;

    const f32x2 qx2 = {qx, qx}, qy2 = {qy, qy}, qz2 = {qz, qz};

    for (int j0 = 0; j0 < 512; j0 += 8) {
        // 8 points = 96B contiguous = 6 dwordx4 (wave-uniform -> broadcast)
        const float4 F0 = *(const float4*)(P + j0 * 3 + 0);
        const float4 F1 = *(const float4*)(P + j0 * 3 + 4);
        const float4 F2 = *(const float4*)(P + j0 * 3 + 8);
        const float4 F3 = *(const float4*)(P + j0 * 3 + 12);
        const float4 F4 = *(const float4*)(P + j0 * 3 + 16);
        const float4 F5 = *(const float4*)(P + j0 * 3 + 20);
        float xf[8];
        {
            // pt u components: 0:(F0.x,F0.y,F0.z) 1:(F0.w,F1.x,F1.y)
            // 2:(F1.z,F1.w,F2.x) 3:(F2.y,F2.z,F2.w) 4:(F3.x,F3.y,F3.z)
            // 5:(F3.w,F4.x,F4.y) 6:(F4.z,F4.w,F5.x) 7:(F5.y,F5.z,F5.w)
            // packed pairs: contract-fast -> v_pk ops (2 pts/instr)
            const f32x2 X01 = {F0.x, F0.w}, Y01 = {F0.y, F1.x}, Z01 = {F0.z, F1.y};
            const f32x2 X23 = {F1.z, F2.y}, Y23 = {F1.w, F2.z}, Z23 = {F2.x, F2.w};
            const f32x2 X45 = {F3.x, F3.w}, Y45 = {F3.y, F4.x}, Z45 = {F3.z, F4.y};
            const f32x2 X67 = {F4.z, F5.y}, Y67 = {F4.w, F5.z}, Z67 = {F5.x, F5.w};
            f32x2 dx, dy, dz, d;
            dx = qx2 - X01; dy = qy2 - Y01; dz = qz2 - Z01;
            d = dx * dx + dy * dy + dz * dz; xf[0] = d.x; xf[1] = d.y;
            dx = qx2 - X23; dy = qy2 - Y23; dz = qz2 - Z23;
            d = dx * dx + dy * dy + dz * dz; xf[2] = d.x; xf[3] = d.y;
            dx = qx2 - X45; dy = qy2 - Y45; dz = qz2 - Z45;
            d = dx * dx + dy * dy + dz * dz; xf[4] = d.x; xf[5] = d.y;
            dx = qx2 - X67; dy = qy2 - Y67; dz = qz2 - Z67;
            d = dx * dx + dy * dy + dz * dz; xf[6] = d.x; xf[7] = d.y;
        }
        // ---- accept + store vs FROZEN threshold * (1+2^-18): superset-safe ----
        const float thr = bd[K_ - 1] * 1.0000038f;
#pragma unroll
        for (int u = 0; u < 8; ++u) {
            const bool acc = xf[u] < thr;
            if (acc) {
                const int capped = cnt < LCAP ? cnt : LCAP;
                sMem[capped * 256 + tid] = (unsigned short)(j0 + u);
                cnt++;
            }
        }
        // ---- value update (loose, threshold-only): sort8 (19 CAS) ----
        CASF(xf[0], xf[1]); CASF(xf[2], xf[3]); CASF(xf[4], xf[5]); CASF(xf[6], xf[7]);
        CASF(xf[0], xf[2]); CASF(xf[1], xf[3]); CASF(xf[4], xf[6]); CASF(xf[5], xf[7]);
        CASF(xf[1], xf[2]); CASF(xf[5], xf[6]); CASF(xf[0], xf[4]); CASF(xf[3], xf[7]);
        CASF(xf[1], xf[5]); CASF(xf[2], xf[6]);
        CASF(xf[1], xf[4]); CASF(xf[3], xf[6]);
        CASF(xf[2], xf[4]); CASF(xf[3], xf[5]);
        CASF(xf[3], xf[4]);
        // ---- bitonic split: lowest-8 of (bd asc ++ xf desc) ----
        float t0 = fminf(bd[0], xf[7]);
        float t1 = fminf(bd[1], xf[6]);
        float t2 = fminf(bd[2], xf[5]);
        float t3 = fminf(bd[3], xf[4]);
        float t4 = fminf(bd[4], xf[3]);
        float t5 = fminf(bd[5], xf[2]);
        float t6 = fminf(bd[6], xf[1]);
        float t7 = fminf(bd[7], xf[0]);
        // ---- bitonic merge-8 (12 CAS) -> bd sorted ascending ----
        CASF(t0, t4); CASF(t1, t5); CASF(t2, t6); CASF(t3, t7);
        CASF(t0, t2); CASF(t1, t3); CASF(t4, t6); CASF(t5, t7);
        CASF(t0, t1); CASF(t2, t3); CASF(t4, t5); CASF(t6, t7);
        bd[0] = t0; bd[1] = t1; bd[2] = t2; bd[3] = t3;
        bd[4] = t4; bd[5] = t5; bd[6] = t6; bd[7] = t7;
    }

    // ---- recovery: replay the verified (d,idx) chain over listed candidates ----
    float rd[K_];
    int   ri[K_];
#pragma unroll
    for (int t = 0; t < K_; ++t) { rd[t] = 3.0e38f; ri[t] = 0; }
    const int m = cnt < LCAP ? cnt : LCAP;
    for (int t = 0;; ++t) {
        const bool act = t < m;
        if (!__any(act)) break;
        if (act) {
#pragma clang fp contract(off)
            const int jl = sMem[t * 256 + tid];
            const float* pp = P + jl * 3;
            const float dx = qx - pp[0];
            const float dy = qy - pp[1];
            const float dz = qz - pp[2];
            const float dx2 = dx * dx;
            const float dy2 = dy * dy;
            const float dz2 = dz * dz;
            const float d2 = (dx2 + dy2) + dz2;
            if (d2 < rd[K_ - 1]) {
                rd[K_ - 1] = d2; ri[K_ - 1] = s * 512 + jl;
#pragma unroll
                for (int t2 = K_ - 1; t2 >= 1; --t2) {
                    if (rd[t2] < rd[t2 - 1]) {
                        float td = rd[t2]; rd[t2] = rd[t2 - 1]; rd[t2 - 1] = td;
                        int   ti = ri[t2]; ri[t2] = ri[t2 - 1]; ri[t2 - 1] = ti;
                    }
                }
            }
        }
    }

    // ---- overflow fallback: full verified scan for the (rare) lane ----
    if (__any(cnt > LCAP)) {
        if (cnt > LCAP) {
#pragma unroll
            for (int t = 0; t < K_; ++t) { rd[t] = 3.0e38f; ri[t] = 0; }
            for (int j = 0; j < 512; ++j) {
#pragma clang fp contract(off)
                const float* pp = P + j * 3;
                const float dx = qx - pp[0];
                const float dy = qy - pp[1];
                const float dz = qz - pp[2];
                const float dx2 = dx * dx;
                const float dy2 = dy * dy;
                const float dz2 = dz * dz;
                const float d2 = (dx2 + dy2) + dz2;
                if (d2 < rd[K_ - 1]) {
                    rd[K_ - 1] = d2; ri[K_ - 1] = s * 512 + j;
#pragma unroll
                    for (int t2 = K_ - 1; t2 >= 1; --t2) {
                        if (rd[t2] < rd[t2 - 1]) {
                            float td = rd[t2]; rd[t2] = rd[t2 - 1]; rd[t2 - 1] = td;
                            int   ti = ri[t2]; ri[t2] = ri[t2 - 1]; ri[t2 - 1] = ti;
                        }
                    }
                }
            }
        }
    }

    __syncthreads();  // lists fully consumed before reusing sMem as merge region
#pragma unroll
    for (int t = 0; t < K_; ++t) {
        sD[lane * 33 + s * 8 + t] = rd[t];
        sI[lane * 33 + s * 8 + t] = ri[t];
    }
    __syncthreads();

    if (tid < 64) {
        const int qq = tid;
        int h[4] = {0, 0, 0, 0};
        const int base = (b * N1_ + t64 * 64 + qq) * K_;
#pragma unroll
        for (int t = 0; t < K_; ++t) {
            float best = 3.1e38f;
            int   bidx = 0, bs = 0;
#pragma unroll
            for (int ss = 0; ss < 4; ++ss) {
                if (h[ss] < 8) {
                    const float d = sD[qq * 33 + ss * 8 + h[ss]];
                    if (d < best) { best = d; bidx = sI[qq * 33 + ss * 8 + h[ss]]; bs = ss; }
                }
            }
#pragma unroll
            for (int ss = 0; ss < 4; ++ss) h[ss] += (ss == bs) ? 1 : 0;
            idx[base + t] = bidx;
        }
    }
}

// ---------------------------------------------------------------------------
// Fused MFMA MLP v3 (r10 verified, byte-identical): N-split waves; A0 K=128
// @ stride 136 + sXyz kstep; A1 in-place; sCat overlay after post-L1
// barrier; feat1 issue-early/write-late. LDS 36864 B => 4 blocks/CU.
// MFMA 16x16x32 bf16; C/D: col=lane&15, row=(lane>>4)*4+reg  [m89-verified]
// ---------------------------------------------------------------------------
__global__ __launch_bounds__(256, 4) void fused_mfma(
    const float* __restrict__ xyz1, const float* __restrict__ xyz2,
    const float* __restrict__ feat1,
    const float* __restrict__ b0, const float* __restrict__ b1,
    const float* __restrict__ b2,
    const short* __restrict__ feat2b, const short* __restrict__ W0T,
    const short* __restrict__ W1T, const short* __restrict__ W2T,
    const int* __restrict__ idx, float* __restrict__ out) {
    __shared__ __align__(16) short sA[128 * 136 + 128 * 8];  // A0/A1 + sXyz; sCat overlay
    short* sXyz = sA + 128 * 136;  // [128][8] bf16: {dx,dy,dz,0,...}
    short* sCat = sA;              // [16][200] overlay after post-L1 barrier

    const int bid = blockIdx.x;
    const int b = bid & 7;           // batch = XCD (round-robin dispatch)
    const int n0 = (bid >> 3) * 16;  // tile within batch
    const int tid = threadIdx.x;

    // ---- feat1 -> registers early (written to sCat after post-L1 barrier) ----
    const float4 f1v = *(const float4*)(feat1 + ((size_t)b * N1_ + n0 + (tid >> 4)) * 64 + (tid & 15) * 4);

    // ---- stage A0 (K=128, stride 136) + sXyz strip ----
    {
        const int row = tid >> 1, half = tid & 1;
        const int p = row >> 3, kk = row & 7;
        const int n = n0 + p;
        const int j = idx[((size_t)b * N1_ + n) * K_ + kk];
        const uint4* src = (const uint4*)(feat2b + ((size_t)(b * N2_ + j)) * 128 + half * 64);
        uint4* dst = (uint4*)(sA + row * 136 + half * 64);
#pragma unroll
        for (int t = 0; t < 8; ++t) dst[t] = src[t];
        if (half == 0) {
            const float dx = xyz2[((size_t)b * N2_ + j) * 3 + 0] - xyz1[((size_t)b * N1_ + n) * 3 + 0];
            const float dy = xyz2[((size_t)b * N2_ + j) * 3 + 1] - xyz1[((size_t)b * N1_ + n) * 3 + 1];
            const float dz = xyz2[((size_t)b * N2_ + j) * 3 + 2] - xyz1[((size_t)b * N1_ + n) * 3 + 2];
            uint4 v;
            v.x = (unsigned short)f2b(dx) | ((unsigned)(unsigned short)f2b(dy) << 16);
            v.y = (unsigned short)f2b(dz);
            v.z = 0; v.w = 0;
            *(uint4*)(sXyz + row * 8) = v;
        }
    }
    __syncthreads();

    const int wave = tid >> 6, lane = tid & 63;
    const int q = lane >> 4, l15 = lane & 15;
    const int mBase = (wave & 1) * 64, nBase = (wave >> 1) * 64;

    const f32x4 zero4 = {0.f, 0.f, 0.f, 0.f};

    // ---------------- Layer 0: K=160 (4 LDS ksteps + 1 sXyz kstep) ---------
    f32x4 acc[4][4];
#pragma unroll
    for (int mt = 0; mt < 4; ++mt)
#pragma unroll
        for (int nt = 0; nt < 4; ++nt) acc[mt][nt] = zero4;

    for (int ks = 0; ks < 4; ++ks) {
        bf16x8 af[4], bf[4];
#pragma unroll
        for (int mt = 0; mt < 4; ++mt)
            af[mt] = *(const bf16x8*)(sA + (mBase + mt * 16 + l15) * 136 + ks * 32 + q * 8);
#pragma unroll
        for (int nt = 0; nt < 4; ++nt)
            bf[nt] = *(const bf16x8*)(W0T + (nBase + nt * 16 + l15) * 160 + ks * 32 + q * 8);
#pragma unroll
        for (int mt = 0; mt < 4; ++mt)
#pragma unroll
            for (int nt = 0; nt < 4; ++nt)
                acc[mt][nt] = __builtin_amdgcn_mfma_f32_16x16x32_bf16(af[mt], bf[nt], acc[mt][nt], 0, 0, 0);
    }
    // kstep 4 (k=128..159): A from sXyz (only q=0's k=128..130 meet nonzero W)
    {
        bf16x8 af[4], bf[4];
#pragma unroll
        for (int mt = 0; mt < 4; ++mt)
            af[mt] = *(const bf16x8*)(sXyz + (mBase + mt * 16 + l15) * 8);
#pragma unroll
        for (int nt = 0; nt < 4; ++nt)
            bf[nt] = *(const bf16x8*)(W0T + (nBase + nt * 16 + l15) * 160 + 128 + q * 8);
#pragma unroll
        for (int mt = 0; mt < 4; ++mt)
#pragma unroll
            for (int nt = 0; nt < 4; ++nt)
                acc[mt][nt] = __builtin_amdgcn_mfma_f32_16x16x32_bf16(af[mt], bf[nt], acc[mt][nt], 0, 0, 0);
    }

    // bias + relu -> A1 overlay (in place, stride 136)
    float b0v[4];
#pragma unroll
    for (int nt = 0; nt < 4; ++nt) b0v[nt] = b0[nBase + nt * 16 + l15];
    __syncthreads();  // all L0 reads of A0 done before overlay writes
#pragma unroll
    for (int mt = 0; mt < 4; ++mt)
#pragma unroll
        for (int nt = 0; nt < 4; ++nt)
#pragma unroll
            for (int r = 0; r < 4; ++r) {
                const int row = mBase + mt * 16 + q * 4 + r;
                const int col = nBase + nt * 16 + l15;
                sA[row * 136 + col] = f2b(fmaxf(acc[mt][nt][r] + b0v[nt], 0.0f));
            }
    __syncthreads();

    // ---------------- Layer 1: K=128 (4 ksteps) ----------------
    f32x4 acc2[4][4];
#pragma unroll
    for (int mt = 0; mt < 4; ++mt)
#pragma unroll
        for (int nt = 0; nt < 4; ++nt) acc2[mt][nt] = zero4;

    for (int ks = 0; ks < 4; ++ks) {
        bf16x8 af[4], bf[4];
#pragma unroll
        for (int mt = 0; mt < 4; ++mt)
            af[mt] = *(const bf16x8*)(sA + (mBase + mt * 16 + l15) * 136 + ks * 32 + q * 8);
#pragma unroll
        for (int nt = 0; nt < 4; ++nt)
            bf[nt] = *(const bf16x8*)(W1T + (nBase + nt * 16 + l15) * 128 + ks * 32 + q * 8);
#pragma unroll
        for (int mt = 0; mt < 4; ++mt)
#pragma unroll
            for (int nt = 0; nt < 4; ++nt)
                acc2[mt][nt] = __builtin_amdgcn_mfma_f32_16x16x32_bf16(af[mt], bf[nt], acc2[mt][nt], 0, 0, 0);
    }

    float b1v[4];
#pragma unroll
    for (int nt = 0; nt < 4; ++nt) b1v[nt] = b1[nBase + nt * 16 + l15];

    __syncthreads();  // A1 fully consumed by all waves before sCat overlay

    // bias + relu + in-register maxpool over 8 neighbors -> sCat cols 0..127
#pragma unroll
    for (int mt = 0; mt < 4; ++mt)
#pragma unroll
        for (int nt = 0; nt < 4; ++nt) {
            float vm = fmaxf(acc2[mt][nt][0] + b1v[nt], 0.0f);
#pragma unroll
            for (int r = 1; r < 4; ++r) vm = fmaxf(vm, acc2[mt][nt][r] + b1v[nt]);
            const float other = __shfl_xor(vm, 16);
            const float pool = fmaxf(vm, other);  // q0/q1 -> even pt, q2/q3 -> odd pt
            if ((q & 1) == 0) {
                const int pp = (mBase >> 3) + mt * 2 + (q >> 1);
                sCat[pp * 200 + nBase + nt * 16 + l15] = f2b(pool);
            }
        }
    // feat1 regs -> sCat cols 128..191 (write-late)
    {
        const int p = tid >> 4;
        const int c4 = (tid & 15) * 4;
        uint2 w;
        w.x = (unsigned short)f2b(f1v.x) | ((unsigned)(unsigned short)f2b(f1v.y) << 16);
        w.y = (unsigned short)f2b(f1v.z) | ((unsigned)(unsigned short)f2b(f1v.w) << 16);
        *(uint2*)(sCat + p * 200 + 128 + c4) = w;
    }
    __syncthreads();  // sCat complete

    // ---------------- Layer 2: M=16 pts, K=192 (6 ksteps), wave owns 32 cols ----
    f32x4 acc3[2];
    acc3[0] = zero4; acc3[1] = zero4;
    const int nB2 = wave * 32;
    for (int ks = 0; ks < 6; ++ks) {
        const bf16x8 a2 = *(const bf16x8*)(sCat + l15 * 200 + ks * 32 + q * 8);
#pragma unroll
        for (int nt = 0; nt < 2; ++nt) {
            const bf16x8 b2f = *(const bf16x8*)(W2T + (nB2 + nt * 16 + l15) * 192 + ks * 32 + q * 8);
            acc3[nt] = __builtin_amdgcn_mfma_f32_16x16x32_bf16(a2, b2f, acc3[nt], 0, 0, 0);
        }
    }
    float b2v[2];
#pragma unroll
    for (int nt = 0; nt < 2; ++nt) b2v[nt] = b2[nB2 + nt * 16 + l15];
#pragma unroll
    for (int nt = 0; nt < 2; ++nt)
#pragma unroll
        for (int r = 0; r < 4; ++r) {
            const int p = q * 4 + r;
            const int col = nB2 + nt * 16 + l15;
            out[((size_t)(b * N1_ + n0 + p)) * 128 + col] = fmaxf(acc3[nt][r] + b2v[nt], 0.0f);
        }
}

extern "C" void kernel_launch(void* const* d_in, const int* in_sizes, int n_in,
                              void* d_out, int out_size, void* d_ws, size_t ws_size,
                              hipStream_t stream) {
    const float* xyz1  = (const float*)d_in[0];
    const float* xyz2  = (const float*)d_in[1];
    const float* feat1 = (const float*)d_in[2];
    const float* feat2 = (const float*)d_in[3];
    const float* W0    = (const float*)d_in[4];
    const float* b0    = (const float*)d_in[5];
    const float* W1    = (const float*)d_in[6];
    const float* b1    = (const float*)d_in[7];
    const float* W2    = (const float*)d_in[8];
    const float* b2    = (const float*)d_in[9];
    float* out = (float*)d_out;

    char* ws = (char*)d_ws;
    int*    idx    = (int*)(ws + 0);            // 2 MB
    short*  feat2b = (short*)(ws + 2097152);    // 4 MB
    short*  W0T    = (short*)(ws + 6291456);    // 40960 B
    short*  W1T    = (short*)(ws + 6332416);    // 32768 B
    short*  W2T    = (short*)(ws + 6365184);    // 49152 B

    // blocks: 1024 knn + 2048 feat2 + 240 weights = 3312
    prep_knn<<<3312, 256, 0, stream>>>(xyz1, xyz2, feat2, W0, W1, W2,
                                       idx, feat2b, W0T, W1T, W2T);
    fused_mfma<<<dim3(8 * (N1_ / 16)), 256, 0, stream>>>(xyz1, xyz2, feat1, b0, b1, b2,
                                                         feat2b, W0T, W1T, W2T, idx, out);
}

// Round 14
// 294.327 us; speedup vs baseline: 1.0544x; 1.0544x over previous
//
#include <hip/hip_runtime.h>
#include <hip/hip_bf16.h>

constexpr int B_  = 8;
constexpr int N1_ = 8192;
constexpr int N2_ = 2048;
constexpr int K_  = 8;

typedef short bf16x8 __attribute__((ext_vector_type(8)));
typedef float f32x4  __attribute__((ext_vector_type(4)));

__device__ __forceinline__ short f2b(float x) {
    __hip_bfloat16 h = __float2bfloat16(x);  // RNE
    return *reinterpret_cast<short*>(&h);
}

// float CAS: for non-negative floats ordering == uint-bit ordering; emits
// v_min_f32/v_max_f32 (2 instr) instead of cmp+2*cndmask.
#define CASF(a, b) { const float _lo = fminf(a, b); \
                     const float _hi = fmaxf(a, b); \
                     (a) = _lo; (b) = _hi; }

// ---------------------------------------------------------------------------
// MERGED prep+knn (r12 verbatim, verified 302.0us total): blocks 0..1023 =
// KNN v9 (AoS broadcast loads, scalar distances); blocks 1024..3071 = feat2
// f32->bf16; blocks 3072..3311 = weights. r13 ERRATA: packed-f32 distances
// REGRESS on AoS loads (pair-building movs > pk savings; VOP3P needs
// even-aligned pairs) — scalar form restored.
// ---------------------------------------------------------------------------
constexpr int LCAP = 76;   // data slots 0..75; rows 76,77 = trash (78 rows)

__global__ __launch_bounds__(256) void prep_knn(
    const float* __restrict__ xyz1, const float* __restrict__ xyz2,
    const float* __restrict__ feat2,
    const float* __restrict__ W0, const float* __restrict__ W1,
    const float* __restrict__ W2,
    int* __restrict__ idx, short* __restrict__ feat2b,
    short* __restrict__ W0T, short* __restrict__ W1T, short* __restrict__ W2T) {
    const int tid = threadIdx.x;

    if (blockIdx.x >= 1024) {
        int i = (blockIdx.x - 1024) * 256 + tid;
        if (i < 2048 * 256) {  // feat2 -> bf16, 4 elems/thread
            const float4 v = ((const float4*)feat2)[i];
            uint2 o;
            o.x = (unsigned short)f2b(v.x) | ((unsigned)(unsigned short)f2b(v.y) << 16);
            o.y = (unsigned short)f2b(v.z) | ((unsigned)(unsigned short)f2b(v.w) << 16);
            ((uint2*)feat2b)[i] = o;
            return;
        }
        i -= 2048 * 256;
        if (i < 128 * 160) {
            const int n = i / 160, k = i % 160;
            W0T[i] = (k < 131) ? f2b(W0[k * 128 + n]) : (short)0;
            return;
        }
        i -= 128 * 160;
        if (i < 128 * 128) {
            const int n = i >> 7, k = i & 127;
            W1T[i] = f2b(W1[k * 128 + n]);
            return;
        }
        i -= 128 * 128;
        const int n = i / 192, k = i % 192;
        W2T[i] = f2b(W2[k * 128 + n]);
        return;
    }

    // ===================== KNN v9 (blocks 0..1023) =========================
    __shared__ __align__(16) unsigned short sMem[78 * 256];  // 39936 B, [slot][tid]
    float* sD = (float*)sMem;             // [64][33] overlay after recovery
    int*   sI = (int*)sMem + 64 * 33;

    const int b = blockIdx.x & 7;        // batch
    const int t64 = blockIdx.x >> 3;     // 64-query tile
    const int lane = tid & 63;           // query within block
    const int s = tid >> 6;              // segment 0..3
    const int n = t64 * 64 + lane;

    const float* q = xyz1 + ((size_t)b * N1_ + n) * 3;
    const float qx = q[0], qy = q[1], qz = q[2];
    const float* P = xyz2 + ((size_t)b * N2_ + s * 512) * 3;  // AoS, 512 pts

    float bd[K_];
#pragma unroll
    for (int t = 0; t < K_; ++t) bd[t] = 3.0e38f;
    int cnt = 0;

    for (int j0 = 0; j0 < 512; j0 += 8) {
        // 8 points = 96B contiguous = 6 dwordx4 (wave-uniform -> broadcast)
        const float4 F0 = *(const float4*)(P + j0 * 3 + 0);
        const float4 F1 = *(const float4*)(P + j0 * 3 + 4);
        const float4 F2 = *(const float4*)(P + j0 * 3 + 8);
        const float4 F3 = *(const float4*)(P + j0 * 3 + 12);
        const float4 F4 = *(const float4*)(P + j0 * 3 + 16);
        const float4 F5 = *(const float4*)(P + j0 * 3 + 20);
        float px[8], py[8], pz[8];
        px[0] = F0.x; py[0] = F0.y; pz[0] = F0.z;
        px[1] = F0.w; py[1] = F1.x; pz[1] = F1.y;
        px[2] = F1.z; py[2] = F1.w; pz[2] = F2.x;
        px[3] = F2.y; py[3] = F2.z; pz[3] = F2.w;
        px[4] = F3.x; py[4] = F3.y; pz[4] = F3.z;
        px[5] = F3.w; py[5] = F4.x; pz[5] = F4.y;
        px[6] = F4.z; py[6] = F4.w; pz[6] = F5.x;
        px[7] = F5.y; py[7] = F5.z; pz[7] = F5.w;
        float xf[8];
#pragma unroll
        for (int u = 0; u < 8; ++u) {
            // contract-fast (filter-only values; threshold margin covers it)
            const float dx = qx - px[u];
            const float dy = qy - py[u];
            const float dz = qz - pz[u];
            xf[u] = dx * dx + dy * dy + dz * dz;
        }
        // ---- accept + store vs FROZEN threshold * (1+2^-18): superset-safe ----
        const float thr = bd[K_ - 1] * 1.0000038f;
#pragma unroll
        for (int u = 0; u < 8; ++u) {
            const bool acc = xf[u] < thr;
            if (acc) {
                const int capped = cnt < LCAP ? cnt : LCAP;
                sMem[capped * 256 + tid] = (unsigned short)(j0 + u);
                cnt++;
            }
        }
        // ---- value update (loose, threshold-only): sort8 (19 CAS) ----
        CASF(xf[0], xf[1]); CASF(xf[2], xf[3]); CASF(xf[4], xf[5]); CASF(xf[6], xf[7]);
        CASF(xf[0], xf[2]); CASF(xf[1], xf[3]); CASF(xf[4], xf[6]); CASF(xf[5], xf[7]);
        CASF(xf[1], xf[2]); CASF(xf[5], xf[6]); CASF(xf[0], xf[4]); CASF(xf[3], xf[7]);
        CASF(xf[1], xf[5]); CASF(xf[2], xf[6]);
        CASF(xf[1], xf[4]); CASF(xf[3], xf[6]);
        CASF(xf[2], xf[4]); CASF(xf[3], xf[5]);
        CASF(xf[3], xf[4]);
        // ---- bitonic split: lowest-8 of (bd asc ++ xf desc) ----
        float t0 = fminf(bd[0], xf[7]);
        float t1 = fminf(bd[1], xf[6]);
        float t2 = fminf(bd[2], xf[5]);
        float t3 = fminf(bd[3], xf[4]);
        float t4 = fminf(bd[4], xf[3]);
        float t5 = fminf(bd[5], xf[2]);
        float t6 = fminf(bd[6], xf[1]);
        float t7 = fminf(bd[7], xf[0]);
        // ---- bitonic merge-8 (12 CAS) -> bd sorted ascending ----
        CASF(t0, t4); CASF(t1, t5); CASF(t2, t6); CASF(t3, t7);
        CASF(t0, t2); CASF(t1, t3); CASF(t4, t6); CASF(t5, t7);
        CASF(t0, t1); CASF(t2, t3); CASF(t4, t5); CASF(t6, t7);
        bd[0] = t0; bd[1] = t1; bd[2] = t2; bd[3] = t3;
        bd[4] = t4; bd[5] = t5; bd[6] = t6; bd[7] = t7;
    }

    // ---- recovery: replay the verified (d,idx) chain over listed candidates ----
    float rd[K_];
    int   ri[K_];
#pragma unroll
    for (int t = 0; t < K_; ++t) { rd[t] = 3.0e38f; ri[t] = 0; }
    const int m = cnt < LCAP ? cnt : LCAP;
    for (int t = 0;; ++t) {
        const bool act = t < m;
        if (!__any(act)) break;
        if (act) {
#pragma clang fp contract(off)
            const int jl = sMem[t * 256 + tid];
            const float* pp = P + jl * 3;
            const float dx = qx - pp[0];
            const float dy = qy - pp[1];
            const float dz = qz - pp[2];
            const float dx2 = dx * dx;
            const float dy2 = dy * dy;
            const float dz2 = dz * dz;
            const float d2 = (dx2 + dy2) + dz2;
            if (d2 < rd[K_ - 1]) {
                rd[K_ - 1] = d2; ri[K_ - 1] = s * 512 + jl;
#pragma unroll
                for (int t2 = K_ - 1; t2 >= 1; --t2) {
                    if (rd[t2] < rd[t2 - 1]) {
                        float td = rd[t2]; rd[t2] = rd[t2 - 1]; rd[t2 - 1] = td;
                        int   ti = ri[t2]; ri[t2] = ri[t2 - 1]; ri[t2 - 1] = ti;
                    }
                }
            }
        }
    }

    // ---- overflow fallback: full verified scan for the (rare) lane ----
    if (__any(cnt > LCAP)) {
        if (cnt > LCAP) {
#pragma unroll
            for (int t = 0; t < K_; ++t) { rd[t] = 3.0e38f; ri[t] = 0; }
            for (int j = 0; j < 512; ++j) {
#pragma clang fp contract(off)
                const float* pp = P + j * 3;
                const float dx = qx - pp[0];
                const float dy = qy - pp[1];
                const float dz = qz - pp[2];
                const float dx2 = dx * dx;
                const float dy2 = dy * dy;
                const float dz2 = dz * dz;
                const float d2 = (dx2 + dy2) + dz2;
                if (d2 < rd[K_ - 1]) {
                    rd[K_ - 1] = d2; ri[K_ - 1] = s * 512 + j;
#pragma unroll
                    for (int t2 = K_ - 1; t2 >= 1; --t2) {
                        if (rd[t2] < rd[t2 - 1]) {
                            float td = rd[t2]; rd[t2] = rd[t2 - 1]; rd[t2 - 1] = td;
                            int   ti = ri[t2]; ri[t2] = ri[t2 - 1]; ri[t2 - 1] = ti;
                        }
                    }
                }
            }
        }
    }

    __syncthreads();  // lists fully consumed before reusing sMem as merge region
#pragma unroll
    for (int t = 0; t < K_; ++t) {
        sD[lane * 33 + s * 8 + t] = rd[t];
        sI[lane * 33 + s * 8 + t] = ri[t];
    }
    __syncthreads();

    if (tid < 64) {
        const int qq = tid;
        int h[4] = {0, 0, 0, 0};
        const int base = (b * N1_ + t64 * 64 + qq) * K_;
#pragma unroll
        for (int t = 0; t < K_; ++t) {
            float best = 3.1e38f;
            int   bidx = 0, bs = 0;
#pragma unroll
            for (int ss = 0; ss < 4; ++ss) {
                if (h[ss] < 8) {
                    const float d = sD[qq * 33 + ss * 8 + h[ss]];
                    if (d < best) { best = d; bidx = sI[qq * 33 + ss * 8 + h[ss]]; bs = ss; }
                }
            }
#pragma unroll
            for (int ss = 0; ss < 4; ++ss) h[ss] += (ss == bs) ? 1 : 0;
            idx[base + t] = bidx;
        }
    }
}

// ---------------------------------------------------------------------------
// Fused MFMA MLP v5 = r10/r12 v3 with ONE change: #pragma unroll 1 on the
// three K-step loops. Theory (r13): fused is I-FETCH-bound — the fully
// unrolled body (~40-60KB text) thrashes the 32KB L1I with 16 resident
// waves at distinct phases; explains all-pipes-idle + occupancy-insensitive
// + "bigger code = slower" (r5/r7/r9/r11). Rolled loops cut text ~3-4x.
// Same MFMA sequence/order => output bit-identical.
// MFMA 16x16x32 bf16; C/D: col=lane&15, row=(lane>>4)*4+reg  [m89-verified]
// ---------------------------------------------------------------------------
__global__ __launch_bounds__(256, 4) void fused_mfma(
    const float* __restrict__ xyz1, const float* __restrict__ xyz2,
    const float* __restrict__ feat1,
    const float* __restrict__ b0, const float* __restrict__ b1,
    const float* __restrict__ b2,
    const short* __restrict__ feat2b, const short* __restrict__ W0T,
    const short* __restrict__ W1T, const short* __restrict__ W2T,
    const int* __restrict__ idx, float* __restrict__ out) {
    __shared__ __align__(16) short sA[128 * 136 + 128 * 8];  // A0/A1 + sXyz; sCat overlay
    short* sXyz = sA + 128 * 136;  // [128][8] bf16: {dx,dy,dz,0,...}
    short* sCat = sA;              // [16][200] overlay after post-L1 barrier

    const int bid = blockIdx.x;
    const int b = bid & 7;           // batch = XCD (round-robin dispatch)
    const int n0 = (bid >> 3) * 16;  // tile within batch
    const int tid = threadIdx.x;

    // ---- feat1 -> registers early (written to sCat after post-L1 barrier) ----
    const float4 f1v = *(const float4*)(feat1 + ((size_t)b * N1_ + n0 + (tid >> 4)) * 64 + (tid & 15) * 4);

    // ---- stage A0 (K=128, stride 136) + sXyz strip ----
    {
        const int row = tid >> 1, half = tid & 1;
        const int p = row >> 3, kk = row & 7;
        const int n = n0 + p;
        const int j = idx[((size_t)b * N1_ + n) * K_ + kk];
        const uint4* src = (const uint4*)(feat2b + ((size_t)(b * N2_ + j)) * 128 + half * 64);
        uint4* dst = (uint4*)(sA + row * 136 + half * 64);
#pragma unroll
        for (int t = 0; t < 8; ++t) dst[t] = src[t];
        if (half == 0) {
            const float dx = xyz2[((size_t)b * N2_ + j) * 3 + 0] - xyz1[((size_t)b * N1_ + n) * 3 + 0];
            const float dy = xyz2[((size_t)b * N2_ + j) * 3 + 1] - xyz1[((size_t)b * N1_ + n) * 3 + 1];
            const float dz = xyz2[((size_t)b * N2_ + j) * 3 + 2] - xyz1[((size_t)b * N1_ + n) * 3 + 2];
            uint4 v;
            v.x = (unsigned short)f2b(dx) | ((unsigned)(unsigned short)f2b(dy) << 16);
            v.y = (unsigned short)f2b(dz);
            v.z = 0; v.w = 0;
            *(uint4*)(sXyz + row * 8) = v;
        }
    }
    __syncthreads();

    const int wave = tid >> 6, lane = tid & 63;
    const int q = lane >> 4, l15 = lane & 15;
    const int mBase = (wave & 1) * 64, nBase = (wave >> 1) * 64;

    const f32x4 zero4 = {0.f, 0.f, 0.f, 0.f};

    // ---------------- Layer 0: K=160 (4 LDS ksteps + 1 sXyz kstep) ---------
    f32x4 acc[4][4];
#pragma unroll
    for (int mt = 0; mt < 4; ++mt)
#pragma unroll
        for (int nt = 0; nt < 4; ++nt) acc[mt][nt] = zero4;

#pragma unroll 1
    for (int ks = 0; ks < 4; ++ks) {
        bf16x8 af[4], bf[4];
#pragma unroll
        for (int mt = 0; mt < 4; ++mt)
            af[mt] = *(const bf16x8*)(sA + (mBase + mt * 16 + l15) * 136 + ks * 32 + q * 8);
#pragma unroll
        for (int nt = 0; nt < 4; ++nt)
            bf[nt] = *(const bf16x8*)(W0T + (nBase + nt * 16 + l15) * 160 + ks * 32 + q * 8);
#pragma unroll
        for (int mt = 0; mt < 4; ++mt)
#pragma unroll
            for (int nt = 0; nt < 4; ++nt)
                acc[mt][nt] = __builtin_amdgcn_mfma_f32_16x16x32_bf16(af[mt], bf[nt], acc[mt][nt], 0, 0, 0);
    }
    // kstep 4 (k=128..159): A from sXyz (only q=0's k=128..130 meet nonzero W)
    {
        bf16x8 af[4], bf[4];
#pragma unroll
        for (int mt = 0; mt < 4; ++mt)
            af[mt] = *(const bf16x8*)(sXyz + (mBase + mt * 16 + l15) * 8);
#pragma unroll
        for (int nt = 0; nt < 4; ++nt)
            bf[nt] = *(const bf16x8*)(W0T + (nBase + nt * 16 + l15) * 160 + 128 + q * 8);
#pragma unroll
        for (int mt = 0; mt < 4; ++mt)
#pragma unroll
            for (int nt = 0; nt < 4; ++nt)
                acc[mt][nt] = __builtin_amdgcn_mfma_f32_16x16x32_bf16(af[mt], bf[nt], acc[mt][nt], 0, 0, 0);
    }

    // bias + relu -> A1 overlay (in place, stride 136)
    float b0v[4];
#pragma unroll
    for (int nt = 0; nt < 4; ++nt) b0v[nt] = b0[nBase + nt * 16 + l15];
    __syncthreads();  // all L0 reads of A0 done before overlay writes
#pragma unroll
    for (int mt = 0; mt < 4; ++mt)
#pragma unroll
        for (int nt = 0; nt < 4; ++nt)
#pragma unroll
            for (int r = 0; r < 4; ++r) {
                const int row = mBase + mt * 16 + q * 4 + r;
                const int col = nBase + nt * 16 + l15;
                sA[row * 136 + col] = f2b(fmaxf(acc[mt][nt][r] + b0v[nt], 0.0f));
            }
    __syncthreads();

    // ---------------- Layer 1: K=128 (4 ksteps) ----------------
    f32x4 acc2[4][4];
#pragma unroll
    for (int mt = 0; mt < 4; ++mt)
#pragma unroll
        for (int nt = 0; nt < 4; ++nt) acc2[mt][nt] = zero4;

#pragma unroll 1
    for (int ks = 0; ks < 4; ++ks) {
        bf16x8 af[4], bf[4];
#pragma unroll
        for (int mt = 0; mt < 4; ++mt)
            af[mt] = *(const bf16x8*)(sA + (mBase + mt * 16 + l15) * 136 + ks * 32 + q * 8);
#pragma unroll
        for (int nt = 0; nt < 4; ++nt)
            bf[nt] = *(const bf16x8*)(W1T + (nBase + nt * 16 + l15) * 128 + ks * 32 + q * 8);
#pragma unroll
        for (int mt = 0; mt < 4; ++mt)
#pragma unroll
            for (int nt = 0; nt < 4; ++nt)
                acc2[mt][nt] = __builtin_amdgcn_mfma_f32_16x16x32_bf16(af[mt], bf[nt], acc2[mt][nt], 0, 0, 0);
    }

    float b1v[4];
#pragma unroll
    for (int nt = 0; nt < 4; ++nt) b1v[nt] = b1[nBase + nt * 16 + l15];

    __syncthreads();  // A1 fully consumed by all waves before sCat overlay

    // bias + relu + in-register maxpool over 8 neighbors -> sCat cols 0..127
#pragma unroll
    for (int mt = 0; mt < 4; ++mt)
#pragma unroll
        for (int nt = 0; nt < 4; ++nt) {
            float vm = fmaxf(acc2[mt][nt][0] + b1v[nt], 0.0f);
#pragma unroll
            for (int r = 1; r < 4; ++r) vm = fmaxf(vm, acc2[mt][nt][r] + b1v[nt]);
            const float other = __shfl_xor(vm, 16);
            const float pool = fmaxf(vm, other);  // q0/q1 -> even pt, q2/q3 -> odd pt
            if ((q & 1) == 0) {
                const int pp = (mBase >> 3) + mt * 2 + (q >> 1);
                sCat[pp * 200 + nBase + nt * 16 + l15] = f2b(pool);
            }
        }
    // feat1 regs -> sCat cols 128..191 (write-late)
    {
        const int p = tid >> 4;
        const int c4 = (tid & 15) * 4;
        uint2 w;
        w.x = (unsigned short)f2b(f1v.x) | ((unsigned)(unsigned short)f2b(f1v.y) << 16);
        w.y = (unsigned short)f2b(f1v.z) | ((unsigned)(unsigned short)f2b(f1v.w) << 16);
        *(uint2*)(sCat + p * 200 + 128 + c4) = w;
    }
    __syncthreads();  // sCat complete

    // ---------------- Layer 2: M=16 pts, K=192 (6 ksteps), wave owns 32 cols ----
    f32x4 acc3[2];
    acc3[0] = zero4; acc3[1] = zero4;
    const int nB2 = wave * 32;
#pragma unroll 1
    for (int ks = 0; ks < 6; ++ks) {
        const bf16x8 a2 = *(const bf16x8*)(sCat + l15 * 200 + ks * 32 + q * 8);
#pragma unroll
        for (int nt = 0; nt < 2; ++nt) {
            const bf16x8 b2f = *(const bf16x8*)(W2T + (nB2 + nt * 16 + l15) * 192 + ks * 32 + q * 8);
            acc3[nt] = __builtin_amdgcn_mfma_f32_16x16x32_bf16(a2, b2f, acc3[nt], 0, 0, 0);
        }
    }
    float b2v[2];
#pragma unroll
    for (int nt = 0; nt < 2; ++nt) b2v[nt] = b2[nB2 + nt * 16 + l15];
#pragma unroll
    for (int nt = 0; nt < 2; ++nt)
#pragma unroll
        for (int r = 0; r < 4; ++r) {
            const int p = q * 4 + r;
            const int col = nB2 + nt * 16 + l15;
            out[((size_t)(b * N1_ + n0 + p)) * 128 + col] = fmaxf(acc3[nt][r] + b2v[nt], 0.0f);
        }
}

extern "C" void kernel_launch(void* const* d_in, const int* in_sizes, int n_in,
                              void* d_out, int out_size, void* d_ws, size_t ws_size,
                              hipStream_t stream) {
    const float* xyz1  = (const float*)d_in[0];
    const float* xyz2  = (const float*)d_in[1];
    const float* feat1 = (const float*)d_in[2];
    const float* feat2 = (const float*)d_in[3];
    const float* W0    = (const float*)d_in[4];
    const float* b0    = (const float*)d_in[5];
    const float* W1    = (const float*)d_in[6];
    const float* b1    = (const float*)d_in[7];
    const float* W2    = (const float*)d_in[8];
    const float* b2    = (const float*)d_in[9];
    float* out = (float*)d_out;

    char* ws = (char*)d_ws;
    int*    idx    = (int*)(ws + 0);            // 2 MB
    short*  feat2b = (short*)(ws + 2097152);    // 4 MB
    short*  W0T    = (short*)(ws + 6291456);    // 40960 B
    short*  W1T    = (short*)(ws + 6332416);    // 32768 B
    short*  W2T    = (short*)(ws + 6365184);    // 49152 B

    // blocks: 1024 knn + 2048 feat2 + 240 weights = 3312
    prep_knn<<<3312, 256, 0, stream>>>(xyz1, xyz2, feat2, W0, W1, W2,
                                       idx, feat2b, W0T, W1T, W2T);
    fused_mfma<<<dim3(8 * (N1_ / 16)), 256, 0, stream>>>(xyz1, xyz2, feat1, b0, b1, b2,
                                                         feat2b, W0T, W1T, W2T, idx, out);
}